// Round 2
// baseline (888.622 us; speedup 1.0000x reference)
//
#include <hip/hip_runtime.h>

// Encoder_8718783611479: stateless LSTMCell => one GEMM + elementwise.
//   gates = xt @ W_ih^T (+b_ih+b_hh); only i,g,o live (f*c_prev=0, W_hh dead)
//   out = sigmoid(sigmoid(o)*tanh(sigmoid(i)*tanh(g)))
// x layout per batch: [k][t], t=240 contiguous floats. MFMA needs k-contiguous
// per lane -> transpose via LDS: stage bf16 xs[t][KP], ds_read_b128 A-frags.
// Stores staged via LDS out-tile -> contiguous dwordx4 (kills partial-line RMW).

#define T_SZ 240
#define K_SZ 180
#define H_SZ 90
#define CHUNK_T 80      // t per block; 3 chunks per batch
#define NTILE 5         // 16-t MFMA tiles per chunk
#define KP 216          // padded k stride (bf16). row=432B: 16B-aligned, bank offset 12 dwords -> 2-way reads (free)

typedef __bf16 bf16x8 __attribute__((ext_vector_type(8)));
typedef float f32x4 __attribute__((ext_vector_type(4)));
typedef float f32x2 __attribute__((ext_vector_type(2)));

__device__ __forceinline__ float sigmoidf_(float x) {
    return 1.0f / (1.0f + __expf(-x));
}
__device__ __forceinline__ float tanhf_(float x) {
    return 1.0f - 2.0f / (__expf(2.0f * x) + 1.0f);
}

__global__ __launch_bounds__(384, 4) void lstm_fused_kernel(
    const float* __restrict__ x,
    const float* __restrict__ W_ih,
    const float* __restrict__ b_ih,
    const float* __restrict__ b_hh,
    float* __restrict__ out)
{
    __shared__ __align__(16) __bf16 xs[CHUNK_T * KP];   // 34,560 B
    __shared__ __align__(16) float obuf[2][16 * H_SZ];  // 11,520 B

    const int b    = blockIdx.x;
    const int t0   = blockIdx.y * CHUNK_T;
    const int tid  = threadIdx.x;
    const int wave = tid >> 6;      // 0..5 -> h-tile
    const int lane = tid & 63;
    const int q    = lane >> 4;     // quad 0..3
    const int n    = lane & 15;
    const int h    = wave * 16 + n;
    const bool hv  = (h < H_SZ);
    const int hcl  = hv ? h : (H_SZ - 1);

    const float* xb = x + (size_t)b * (K_SZ * T_SZ) + t0;  // row k at xb[k*240 + t]

    // ---- stage x chunk -> LDS bf16 (transpose [k][t] -> [t][k]) ----
    // dwordx2 loads: 180 rows x 40 float2 = 7200; fully coalesced.
    for (int j = tid; j < K_SZ * (CHUNK_T / 2); j += 384) {
        int k  = j / (CHUNK_T / 2);
        int tp = j - k * (CHUNK_T / 2);
        f32x2 v = *(const f32x2*)(xb + k * T_SZ + 2 * tp);
        xs[(2 * tp)     * KP + k] = (__bf16)v[0];   // HW RNE cvt
        xs[(2 * tp + 1) * KP + k] = (__bf16)v[1];
    }
    // zero k-pad [180,192) (read by ks=5 fragments)
    for (int i = tid; i < CHUNK_T * 12; i += 384) {
        int t = i / 12;
        int k = K_SZ + (i - t * 12);
        xs[t * KP + k] = (__bf16)0.0f;
    }

    // ---- W fragments (register-resident, 3 gates x 6 ks) ----
    bf16x8 bfrag[3][6];
    const int gb[3] = {0, 180, 270};   // i, g, o row bases in W_ih
    #pragma unroll
    for (int g = 0; g < 3; ++g) {
        const float* wrow = W_ih + (size_t)(gb[g] + hcl) * K_SZ;
        #pragma unroll
        for (int ks = 0; ks < 6; ++ks) {
            const int kb = ks * 32 + q * 8;
            bf16x8 f;
            if (kb + 8 <= K_SZ) {           // uniform within quad-row
                f32x4 lo = *(const f32x4*)(wrow + kb);
                f32x4 hi = *(const f32x4*)(wrow + kb + 4);
                f[0]=(__bf16)lo[0]; f[1]=(__bf16)lo[1]; f[2]=(__bf16)lo[2]; f[3]=(__bf16)lo[3];
                f[4]=(__bf16)hi[0]; f[5]=(__bf16)hi[1]; f[6]=(__bf16)hi[2]; f[7]=(__bf16)hi[3];
            } else {
                #pragma unroll
                for (int j2 = 0; j2 < 8; ++j2) {
                    int k = kb + j2;
                    f[j2] = (__bf16)((k < K_SZ) ? wrow[k] : 0.0f);
                }
            }
            bfrag[g][ks] = f;
        }
    }

    const float bias_i = b_ih[hcl]       + b_hh[hcl];
    const float bias_g = b_ih[180 + hcl] + b_hh[180 + hcl];
    const float bias_o = b_ih[270 + hcl] + b_hh[270 + hcl];

    float* otile = out + (size_t)b * (T_SZ * H_SZ) + (size_t)t0 * H_SZ;

    __syncthreads();   // xs ready

    #pragma unroll 1
    for (int mt = 0; mt < NTILE; ++mt) {
        const __bf16* arow = xs + (mt * 16 + n) * KP;
        f32x4 acc0 = {0.f,0.f,0.f,0.f};
        f32x4 acc1 = {0.f,0.f,0.f,0.f};
        f32x4 acc2 = {0.f,0.f,0.f,0.f};
        #pragma unroll
        for (int ks = 0; ks < 6; ++ks) {
            bf16x8 a = *(const bf16x8*)(arow + ks * 32 + q * 8);  // ds_read_b128
            acc0 = __builtin_amdgcn_mfma_f32_16x16x32_bf16(a, bfrag[0][ks], acc0, 0, 0, 0);
            acc1 = __builtin_amdgcn_mfma_f32_16x16x32_bf16(a, bfrag[1][ks], acc1, 0, 0, 0);
            acc2 = __builtin_amdgcn_mfma_f32_16x16x32_bf16(a, bfrag[2][ks], acc2, 0, 0, 0);
        }

        // epilogue -> LDS out-tile (C/D: col=lane&15 (=h), row=q*4+e (=t))
        const int p = mt & 1;
        #pragma unroll
        for (int e = 0; e < 4; ++e) {
            int row = q * 4 + e;
            float gi = acc0[e] + bias_i;
            float gg = acc1[e] + bias_g;
            float go = acc2[e] + bias_o;
            float c  = sigmoidf_(gi) * tanhf_(gg);
            float hh = sigmoidf_(go) * tanhf_(c);
            float v  = sigmoidf_(hh);
            if (hv) obuf[p][row * H_SZ + h] = v;
        }
        __syncthreads();   // obuf[p] complete (also fences prev tile's readback)

        // contiguous 5760-B tile store: full cache lines, no RMW
        if (tid < 360) {
            f32x4 v4 = *(const f32x4*)&obuf[p][tid * 4];
            *(f32x4*)(otile + mt * (16 * H_SZ) + tid * 4) = v4;
        }
    }
}

extern "C" void kernel_launch(void* const* d_in, const int* in_sizes, int n_in,
                              void* d_out, int out_size, void* d_ws, size_t ws_size,
                              hipStream_t stream) {
    const float* x    = (const float*)d_in[0];
    const float* W_ih = (const float*)d_in[1];
    // d_in[2] = W_hh: dead (h0 = c0 = 0 at every timestep)
    const float* b_ih = (const float*)d_in[3];
    const float* b_hh = (const float*)d_in[4];
    float* out = (float*)d_out;

    lstm_fused_kernel<<<dim3(2048, 3), dim3(384), 0, stream>>>(x, W_ih, b_ih, b_hh, out);
}